// Round 2
// baseline (77.877 us; speedup 1.0000x reference)
//
#include <hip/hip_runtime.h>
#include <hip/hip_bf16.h>

// Hybrid quantum autoencoder, light-cone-reduced.
// Exact reduction: measured observables Z_0..Z_3 have backward light cone
// confined to wires {0..4}; simulate a 5-qubit (32-amp) state per batch
// element entirely in registers. One thread = one batch element.

__global__ __launch_bounds__(64) void qae_kernel(
    const float* __restrict__ inputs,   // (B,12) - only cols 0..4 used
    const float* __restrict__ qp,       // (2,12,3)
    const float* __restrict__ W1,       // (32,4)
    const float* __restrict__ b1,       // (32,)
    const float* __restrict__ W2,       // (12,32)
    const float* __restrict__ b2,       // (12,)
    float* __restrict__ out,            // (B,12)
    int B)
{
    int b = blockIdx.x * blockDim.x + threadIdx.x;
    if (b >= B) return;
    const float* x = inputs + (size_t)b * 12;

    // ---- initial product state: RX(x_j)|0> = [cos(x/2), -i sin(x/2)] ----
    float cj[5], sj[5];
#pragma unroll
    for (int j = 0; j < 5; ++j) {
        sincosf(0.5f * x[j], &sj[j], &cj[j]);
    }

    float sr[32], si[32];
#pragma unroll
    for (int idx = 0; idx < 32; ++idx) {
        float m = 1.0f;
#pragma unroll
        for (int j = 0; j < 5; ++j) m *= ((idx >> j) & 1) ? sj[j] : cj[j];
        int pc = __popc(idx) & 3;           // phase (-i)^popcount
        sr[idx] = (pc == 0) ? m : ((pc == 2) ? -m : 0.0f);
        si[idx] = (pc == 1) ? -m : ((pc == 3) ? m : 0.0f);
    }

    // ---- 2 layers: Rot(phi,theta,omega) on wires 0..4, CNOT chain 0..3 ----
#pragma unroll
    for (int l = 0; l < 2; ++l) {
#pragma unroll
        for (int w = 0; w < 5; ++w) {
            const float* p = qp + (l * 12 + w) * 3;
            float phi = p[0], th = p[1], om = p[2];
            float st, ct;  sincosf(0.5f * th, &st, &ct);
            float sha, cha; sincosf(0.5f * (phi + om), &sha, &cha);
            float shb, chb; sincosf(0.5f * (phi - om), &shb, &chb);
            // Rot = RZ(om) RY(th) RZ(phi):
            // u00 = e^{-i(phi+om)/2} c ; u01 = -conj(e^{-i(phi-om)/2}) s
            // u10 = e^{-i(phi-om)/2} s ; u11 = conj(e^{-i(phi+om)/2}) c
            float u00r =  cha * ct, u00i = -sha * ct;
            float u01r = -chb * st, u01i = -shb * st;
            float u10r =  chb * st, u10i = -shb * st;
            float u11r =  cha * ct, u11i =  sha * ct;
#pragma unroll
            for (int k = 0; k < 16; ++k) {
                int i0 = ((k >> w) << (w + 1)) | (k & ((1 << w) - 1));
                int i1 = i0 | (1 << w);
                float a0r = sr[i0], a0i = si[i0];
                float a1r = sr[i1], a1i = si[i1];
                sr[i0] = u00r * a0r - u00i * a0i + u01r * a1r - u01i * a1i;
                si[i0] = u00r * a0i + u00i * a0r + u01r * a1i + u01i * a1r;
                sr[i1] = u10r * a0r - u10i * a0i + u11r * a1r - u11i * a1i;
                si[i1] = u10r * a0i + u10i * a0r + u11r * a1i + u11i * a1r;
            }
        }
        // CNOT(cw, cw+1): for bit_cw==1, swap target bit — free (reg rename)
#pragma unroll
        for (int cw = 0; cw < 4; ++cw) {
#pragma unroll
            for (int idx = 0; idx < 32; ++idx) {
                if (((idx >> cw) & 1) && !((idx >> (cw + 1)) & 1)) {
                    int j2 = idx | (1 << (cw + 1));
                    float tr = sr[idx]; sr[idx] = sr[j2]; sr[j2] = tr;
                    float ti = si[idx]; si[idx] = si[j2]; si[j2] = ti;
                }
            }
        }
    }

    // ---- Z expvals on wires 0..3 ----
    float lat[4] = {0.f, 0.f, 0.f, 0.f};
#pragma unroll
    for (int idx = 0; idx < 32; ++idx) {
        float pr = sr[idx] * sr[idx] + si[idx] * si[idx];
#pragma unroll
        for (int q = 0; q < 4; ++q)
            lat[q] += ((idx >> q) & 1) ? -pr : pr;
    }

    // ---- MLP: relu(lat @ W1^T + b1) @ W2^T + b2 ----
    float o[12];
#pragma unroll
    for (int j = 0; j < 12; ++j) o[j] = b2[j];
#pragma unroll
    for (int u = 0; u < 32; ++u) {
        float acc = b1[u];
#pragma unroll
        for (int i = 0; i < 4; ++i) acc += lat[i] * W1[u * 4 + i];
        float h = fmaxf(acc, 0.0f);
#pragma unroll
        for (int j = 0; j < 12; ++j) o[j] += h * W2[j * 32 + u];
    }

    float* op = out + (size_t)b * 12;
#pragma unroll
    for (int j = 0; j < 12; ++j) op[j] = o[j];
}

extern "C" void kernel_launch(void* const* d_in, const int* in_sizes, int n_in,
                              void* d_out, int out_size, void* d_ws, size_t ws_size,
                              hipStream_t stream) {
    const float* inputs = (const float*)d_in[0];
    const float* qp     = (const float*)d_in[1];
    const float* W1     = (const float*)d_in[2];
    const float* b1     = (const float*)d_in[3];
    const float* W2     = (const float*)d_in[4];
    const float* b2     = (const float*)d_in[5];
    float* out = (float*)d_out;

    int B = in_sizes[0] / 12;           // 8192
    int block = 64;
    int grid = (B + block - 1) / block; // 128
    qae_kernel<<<grid, block, 0, stream>>>(inputs, qp, W1, b1, W2, b2, out, B);
}

// Round 4
// 76.182 us; speedup vs baseline: 1.0222x; 1.0222x over previous
//
#include <hip/hip_runtime.h>
#include <hip/hip_bf16.h>

// Hybrid quantum autoencoder, light-cone-reduced.
// Exact reduction: measured observables Z_0..Z_3 have backward light cone
// confined to wires {0..4}; simulate a 5-qubit (32-amp) state per batch
// element entirely in registers. One thread = one batch element.
//
// R2 -> R3: replace libm sincosf (slow precise OCML path, ~100+ instrs each,
// 35 calls/thread) with native v_sin/v_cos intrinsics; vectorize row I/O.
// Kernel is latency-bound (1 wave/SIMD), so serial instruction count is
// the whole game.

__device__ __forceinline__ void fsincos(float x, float& s, float& c) {
    s = __sinf(x);   // v_sin_f32 (native), ~1e-6 err for |x| < few*pi*2
    c = __cosf(x);   // v_cos_f32
}

__global__ __launch_bounds__(64) void qae_kernel(
    const float* __restrict__ inputs,   // (B,12) - only cols 0..4 used
    const float* __restrict__ qp,       // (2,12,3)
    const float* __restrict__ W1,       // (32,4)
    const float* __restrict__ b1,       // (32,)
    const float* __restrict__ W2,       // (12,32)
    const float* __restrict__ b2,       // (12,)
    float* __restrict__ out,            // (B,12)
    int B)
{
    int b = blockIdx.x * blockDim.x + threadIdx.x;
    if (b >= B) return;
    const float* x = inputs + (size_t)b * 12;

    // ---- vectorized input row load: x0..x3 + x4 (row stride 48B, 16B-aligned)
    float4 xv = *reinterpret_cast<const float4*>(x);
    float x4 = x[4];

    // ---- initial product state: RX(x_j)|0> = [cos(x/2), -i sin(x/2)] ----
    float cj[5], sj[5];
    fsincos(0.5f * xv.x, sj[0], cj[0]);
    fsincos(0.5f * xv.y, sj[1], cj[1]);
    fsincos(0.5f * xv.z, sj[2], cj[2]);
    fsincos(0.5f * xv.w, sj[3], cj[3]);
    fsincos(0.5f * x4,   sj[4], cj[4]);

    float sr[32], si[32];
#pragma unroll
    for (int idx = 0; idx < 32; ++idx) {
        float m = 1.0f;
#pragma unroll
        for (int j = 0; j < 5; ++j) m *= ((idx >> j) & 1) ? sj[j] : cj[j];
        int pc = __popc(idx) & 3;           // phase (-i)^popcount
        sr[idx] = (pc == 0) ? m : ((pc == 2) ? -m : 0.0f);
        si[idx] = (pc == 1) ? -m : ((pc == 3) ? m : 0.0f);
    }

    // ---- 2 layers: Rot(phi,theta,omega) on wires 0..4, CNOT chain 0..3 ----
#pragma unroll
    for (int l = 0; l < 2; ++l) {
#pragma unroll
        for (int w = 0; w < 5; ++w) {
            const float* p = qp + (l * 12 + w) * 3;  // uniform -> s_load
            float phi = p[0], th = p[1], om = p[2];
            float st, ct, sha, cha, shb, chb;
            fsincos(0.5f * th, st, ct);
            fsincos(0.5f * (phi + om), sha, cha);
            fsincos(0.5f * (phi - om), shb, chb);
            // Rot = RZ(om) RY(th) RZ(phi):
            // u00 = e^{-i(phi+om)/2} c ; u01 = -conj(e^{-i(phi-om)/2}) s
            // u10 = e^{-i(phi-om)/2} s ; u11 = conj(e^{-i(phi+om)/2}) c
            float u00r =  cha * ct, u00i = -sha * ct;
            float u01r = -chb * st, u01i = -shb * st;
            float u10r =  chb * st, u10i = -shb * st;
            float u11r =  cha * ct, u11i =  sha * ct;
#pragma unroll
            for (int k = 0; k < 16; ++k) {
                int i0 = ((k >> w) << (w + 1)) | (k & ((1 << w) - 1));
                int i1 = i0 | (1 << w);
                float a0r = sr[i0], a0i = si[i0];
                float a1r = sr[i1], a1i = si[i1];
                sr[i0] = u00r * a0r - u00i * a0i + u01r * a1r - u01i * a1i;
                si[i0] = u00r * a0i + u00i * a0r + u01r * a1i + u01i * a1r;
                sr[i1] = u10r * a0r - u10i * a0i + u11r * a1r - u11i * a1i;
                si[i1] = u10r * a0i + u10i * a0r + u11r * a1i + u11i * a1r;
            }
        }
        // CNOT(cw, cw+1): for bit_cw==1, flip target bit — free (reg rename)
#pragma unroll
        for (int cw = 0; cw < 4; ++cw) {
#pragma unroll
            for (int idx = 0; idx < 32; ++idx) {
                if (((idx >> cw) & 1) && !((idx >> (cw + 1)) & 1)) {
                    int j2 = idx | (1 << (cw + 1));
                    float tr = sr[idx]; sr[idx] = sr[j2]; sr[j2] = tr;
                    float ti = si[idx]; si[idx] = si[j2]; si[j2] = ti;
                }
            }
        }
    }

    // ---- Z expvals on wires 0..3 ----
    float lat[4] = {0.f, 0.f, 0.f, 0.f};
#pragma unroll
    for (int idx = 0; idx < 32; ++idx) {
        float pr = sr[idx] * sr[idx] + si[idx] * si[idx];
#pragma unroll
        for (int q = 0; q < 4; ++q)
            lat[q] += ((idx >> q) & 1) ? -pr : pr;
    }

    // ---- MLP: relu(lat @ W1^T + b1) @ W2^T + b2 ----
    float o[12];
#pragma unroll
    for (int j = 0; j < 12; ++j) o[j] = b2[j];
#pragma unroll
    for (int u = 0; u < 32; ++u) {
        float acc = b1[u];
#pragma unroll
        for (int i = 0; i < 4; ++i) acc += lat[i] * W1[u * 4 + i];
        float h = fmaxf(acc, 0.0f);
#pragma unroll
        for (int j = 0; j < 12; ++j) o[j] += h * W2[j * 32 + u];
    }

    // ---- vectorized output row store (stride 48B, 16B-aligned) ----
    float4* op = reinterpret_cast<float4*>(out + (size_t)b * 12);
    op[0] = make_float4(o[0], o[1], o[2], o[3]);
    op[1] = make_float4(o[4], o[5], o[6], o[7]);
    op[2] = make_float4(o[8], o[9], o[10], o[11]);
}

extern "C" void kernel_launch(void* const* d_in, const int* in_sizes, int n_in,
                              void* d_out, int out_size, void* d_ws, size_t ws_size,
                              hipStream_t stream) {
    const float* inputs = (const float*)d_in[0];
    const float* qp     = (const float*)d_in[1];
    const float* W1     = (const float*)d_in[2];
    const float* b1     = (const float*)d_in[3];
    const float* W2     = (const float*)d_in[4];
    const float* b2     = (const float*)d_in[5];
    float* out = (float*)d_out;

    int B = in_sizes[0] / 12;           // 8192
    int block = 64;
    int grid = (B + block - 1) / block; // 128
    qae_kernel<<<grid, block, 0, stream>>>(inputs, qp, W1, b1, W2, b2, out, B);
}

// Round 6
// 65.615 us; speedup vs baseline: 1.1869x; 1.1610x over previous
//
#include <hip/hip_runtime.h>
#include <hip/hip_bf16.h>

// Hybrid quantum autoencoder, light-cone-reduced (exact 5-qubit reduction).
// R4 -> R5: parallelize each batch element across 8 lanes (4 amps per lane).
// Amp index idx = (sub<<2)|r : bits 0,1 (wires 0,1) in-register (r),
// bits 2,3,4 (wires 2,3,4) = lane-in-group bits (sub). Cross-lane gate
// pairs and CNOTs via __shfl_xor; MLP split 4 hidden units/lane + butterfly.
// 65536 threads = 1024 waves -> all 1024 SIMDs occupied (vs 128 waves before).

__device__ __forceinline__ void fsincos(float x, float& s, float& c) {
    s = __sinf(x);   // native v_sin_f32
    c = __cosf(x);   // native v_cos_f32
}

__global__ __launch_bounds__(256) void qae_kernel(
    const float* __restrict__ inputs,   // (B,12) - only cols 0..4 used
    const float* __restrict__ qp,       // (2,12,3)
    const float* __restrict__ W1,       // (32,4)
    const float* __restrict__ b1,       // (32,)
    const float* __restrict__ W2,       // (12,32)
    const float* __restrict__ b2,       // (12,)
    float* __restrict__ out,            // (B,12)
    int B)
{
    int tid = blockIdx.x * blockDim.x + threadIdx.x;
    int e   = tid >> 3;      // batch element
    int sub = tid & 7;       // lane within 8-lane group
    if (e >= B) return;

    const float* x = inputs + (size_t)e * 12;
    float4 xv = *reinterpret_cast<const float4*>(x);  // rows are 48B, 16B-aligned
    float x4 = x[4];

    // ---- initial product state: RX(x_j)|0> = [cos(x/2), -i sin(x/2)] ----
    float cj[5], sj[5];
    fsincos(0.5f * xv.x, sj[0], cj[0]);
    fsincos(0.5f * xv.y, sj[1], cj[1]);
    fsincos(0.5f * xv.z, sj[2], cj[2]);
    fsincos(0.5f * xv.w, sj[3], cj[3]);
    fsincos(0.5f * x4,   sj[4], cj[4]);

    // sub-dependent factor (wires 2,3,4), shared by all 4 amps of this lane
    float fsub = ((sub & 1) ? sj[2] : cj[2])
               * ((sub & 2) ? sj[3] : cj[3])
               * ((sub & 4) ? sj[4] : cj[4]);

    float ar[4], ai[4];
#pragma unroll
    for (int r = 0; r < 4; ++r) {
        float m = fsub * ((r & 1) ? sj[0] : cj[0]) * ((r & 2) ? sj[1] : cj[1]);
        int pc = (__popc(sub) + __popc(r)) & 3;   // phase (-i)^popcount(idx)
        ar[r] = (pc == 0) ? m : ((pc == 2) ? -m : 0.0f);
        ai[r] = (pc == 1) ? -m : ((pc == 3) ? m : 0.0f);
    }

#define APPLY_PAIR(i0, i1)                                        \
    {                                                             \
        float a0r = ar[i0], a0i = ai[i0];                         \
        float a1r = ar[i1], a1i = ai[i1];                         \
        ar[i0] = u00r*a0r - u00i*a0i + u01r*a1r - u01i*a1i;       \
        ai[i0] = u00r*a0i + u00i*a0r + u01r*a1i + u01i*a1r;       \
        ar[i1] = u10r*a0r - u10i*a0i + u11r*a1r - u11i*a1i;       \
        ai[i1] = u10r*a0i + u10i*a0r + u11r*a1i + u11i*a1r;       \
    }

    // ---- 2 layers: Rot on wires 0..4, CNOT chain 0..3 ----
#pragma unroll
    for (int l = 0; l < 2; ++l) {
#pragma unroll
        for (int w = 0; w < 5; ++w) {
            const float* p = qp + (l * 12 + w) * 3;   // wave-uniform -> s_load
            float phi = p[0], th = p[1], om = p[2];
            float st, ct, sha, cha, shb, chb;
            fsincos(0.5f * th, st, ct);
            fsincos(0.5f * (phi + om), sha, cha);
            fsincos(0.5f * (phi - om), shb, chb);
            // Rot = RZ(om) RY(th) RZ(phi)
            float u00r =  cha * ct, u00i = -sha * ct;
            float u01r = -chb * st, u01i = -shb * st;
            float u10r =  chb * st, u10i = -shb * st;
            float u11r =  cha * ct, u11i =  sha * ct;

            if (w == 0) {            // bit0 of r: pairs (0,1),(2,3)
                APPLY_PAIR(0, 1);
                APPLY_PAIR(2, 3);
            } else if (w == 1) {     // bit1 of r: pairs (0,2),(1,3)
                APPLY_PAIR(0, 2);
                APPLY_PAIR(1, 3);
            } else {                 // wires 2..4 live on lane bits 0..2
                int lm = 1 << (w - 2);
                bool hi = (sub >> (w - 2)) & 1;
                // hi=0 holds i0: a' = u00*mine + u01*theirs
                // hi=1 holds i1: a' = u11*mine + u10*theirs
                float cmr = hi ? u11r : u00r, cmi = hi ? u11i : u00i;
                float ctr = hi ? u10r : u01r, cti = hi ? u10i : u01i;
#pragma unroll
                for (int r = 0; r < 4; ++r) {
                    float tr = __shfl_xor(ar[r], lm, 64);
                    float ti = __shfl_xor(ai[r], lm, 64);
                    float nr = cmr*ar[r] - cmi*ai[r] + ctr*tr - cti*ti;
                    float ni = cmr*ai[r] + cmi*ar[r] + ctr*ti + cti*tr;
                    ar[r] = nr; ai[r] = ni;
                }
            }
        }

        // CNOT(0,1): ctrl bit0, tgt bit1 -> swap amps r=1 <-> r=3 (in-reg)
        { float t;
          t = ar[1]; ar[1] = ar[3]; ar[3] = t;
          t = ai[1]; ai[1] = ai[3]; ai[3] = t; }

        // CNOT(1,2): ctrl bit1 (r in {2,3}), tgt lane bit0 -> unconditional
        // exchange of r=2,3 with lane^1 (both partners have ctrl=1)
        ar[2] = __shfl_xor(ar[2], 1, 64); ai[2] = __shfl_xor(ai[2], 1, 64);
        ar[3] = __shfl_xor(ar[3], 1, 64); ai[3] = __shfl_xor(ai[3], 1, 64);

        // CNOT(2,3): ctrl lane bit0, tgt lane bit1 -> lanes with bit0=1 swap
        // all 4 amps with lane^2 (partner shares bit0)
        {
            bool c = (sub & 1);
#pragma unroll
            for (int r = 0; r < 4; ++r) {
                float tr = __shfl_xor(ar[r], 2, 64);
                float ti = __shfl_xor(ai[r], 2, 64);
                if (c) { ar[r] = tr; ai[r] = ti; }
            }
        }

        // CNOT(3,4): ctrl lane bit1, tgt lane bit2 -> lanes with bit1=1 swap
        // with lane^4 (partner shares bit1)
        {
            bool c = (sub & 2);
#pragma unroll
            for (int r = 0; r < 4; ++r) {
                float tr = __shfl_xor(ar[r], 4, 64);
                float ti = __shfl_xor(ai[r], 4, 64);
                if (c) { ar[r] = tr; ai[r] = ti; }
            }
        }
    }
#undef APPLY_PAIR

    // ---- Z expvals on wires 0..3 ----
    float p0 = ar[0]*ar[0] + ai[0]*ai[0];
    float p1 = ar[1]*ar[1] + ai[1]*ai[1];
    float p2 = ar[2]*ar[2] + ai[2]*ai[2];
    float p3 = ar[3]*ar[3] + ai[3]*ai[3];
    float l0 = p0 - p1 + p2 - p3;               // wire0 = bit0 of r
    float l1 = p0 + p1 - p2 - p3;               // wire1 = bit1 of r
    float sp = p0 + p1 + p2 + p3;
    float l2 = (sub & 1) ? -sp : sp;            // wire2 = lane bit0
    float l3 = (sub & 2) ? -sp : sp;            // wire3 = lane bit1
#pragma unroll
    for (int m = 1; m <= 4; m <<= 1) {
        l0 += __shfl_xor(l0, m, 64);
        l1 += __shfl_xor(l1, m, 64);
        l2 += __shfl_xor(l2, m, 64);
        l3 += __shfl_xor(l3, m, 64);
    }

    // ---- MLP: relu(lat @ W1^T + b1) @ W2^T + b2, 4 hidden units per lane ----
    float4 b1v = reinterpret_cast<const float4*>(b1)[sub];
    float b1k[4] = {b1v.x, b1v.y, b1v.z, b1v.w};
    float h[4];
#pragma unroll
    for (int k = 0; k < 4; ++k) {
        float4 w = reinterpret_cast<const float4*>(W1)[4 * sub + k];
        float acc = b1k[k] + l0*w.x + l1*w.y + l2*w.z + l3*w.w;
        h[k] = fmaxf(acc, 0.0f);
    }
    float o[12];
#pragma unroll
    for (int j = 0; j < 12; ++j) {
        float4 w2 = *reinterpret_cast<const float4*>(W2 + 32*j + 4*sub);
        o[j] = h[0]*w2.x + h[1]*w2.y + h[2]*w2.z + h[3]*w2.w;
    }
#pragma unroll
    for (int m = 1; m <= 4; m <<= 1) {
#pragma unroll
        for (int j = 0; j < 12; ++j) o[j] += __shfl_xor(o[j], m, 64);
    }

    if (sub == 0) {
        float4* op = reinterpret_cast<float4*>(out + (size_t)e * 12);
        op[0] = make_float4(o[0]+b2[0], o[1]+b2[1], o[2]+b2[2],  o[3]+b2[3]);
        op[1] = make_float4(o[4]+b2[4], o[5]+b2[5], o[6]+b2[6],  o[7]+b2[7]);
        op[2] = make_float4(o[8]+b2[8], o[9]+b2[9], o[10]+b2[10], o[11]+b2[11]);
    }
}

extern "C" void kernel_launch(void* const* d_in, const int* in_sizes, int n_in,
                              void* d_out, int out_size, void* d_ws, size_t ws_size,
                              hipStream_t stream) {
    const float* inputs = (const float*)d_in[0];
    const float* qp     = (const float*)d_in[1];
    const float* W1     = (const float*)d_in[2];
    const float* b1     = (const float*)d_in[3];
    const float* W2     = (const float*)d_in[4];
    const float* b2     = (const float*)d_in[5];
    float* out = (float*)d_out;

    int B = in_sizes[0] / 12;                 // 8192
    int threads = B * 8;                      // 8 lanes per element
    int block = 256;
    int grid = (threads + block - 1) / block; // 256
    qae_kernel<<<grid, block, 0, stream>>>(inputs, qp, W1, b1, W2, b2, out, B);
}